// Round 1
// baseline (21900.204 us; speedup 1.0000x reference)
//
#include <hip/hip_runtime.h>

#define T_SEQ   1024
#define T_STEPS 1023
#define BATCH   128
#define DIM     256
#define HID     1024
#define VOUT    128
#define KTOT    1280   // 256 (x) + 1024 (h)

typedef __attribute__((ext_vector_type(8))) short short8;
typedef __attribute__((ext_vector_type(4))) float floatx4;

__device__ __forceinline__ unsigned short f2bf(float x) {
    union { float f; unsigned u; } v; v.f = x;
    unsigned r = v.u + 0x7FFFu + ((v.u >> 16) & 1u);   // RNE
    return (unsigned short)(r >> 16);
}
__device__ __forceinline__ float sigm(float x) { return 1.0f / (1.0f + __expf(-x)); }

// ---------------- prep kernels (run every call; cheap, parallel) ----------------

// Pack gate weights, bf16, k-contiguous per gathered gate column.
// WG g7 owns h-cols [g7*8, g7*8+8); its 32 gate cols are c = gate*8 + jj,
// mapping to W row R = gate*1024 + g7*8 + jj. k<256 -> W_ih, k>=256 -> W_hh.
__global__ void pack_w(const float* __restrict__ Wih, const float* __restrict__ Whh,
                       unsigned short* __restrict__ Wp) {
    const size_t idx = (size_t)blockIdx.x * 256 + threadIdx.x;
    if (idx >= (size_t)128 * 32 * KTOT) return;
    const int k  = (int)(idx % KTOT);
    const int gc = (int)(idx / KTOT);
    const int c  = gc & 31;
    const int g7 = gc >> 5;
    const int gate = c >> 3;
    const int jj   = c & 7;
    const int R = gate * HID + g7 * 8 + jj;
    const float v = (k < DIM) ? Wih[(size_t)R * DIM + k] : Whh[(size_t)R * HID + (k - DIM)];
    Wp[idx] = f2bf(v);
}

__global__ void pack_bias(const float* __restrict__ bih, const float* __restrict__ bhh,
                          float* __restrict__ bc) {
    const int idx = blockIdx.x * 256 + threadIdx.x;
    if (idx >= 4096) return;
    const int c = idx & 31, g7 = idx >> 5;
    const int gate = c >> 3, jj = c & 7;
    const int R = gate * HID + g7 * 8 + jj;
    bc[idx] = bih[R] + bhh[R];
}

__global__ void pack_wout(const float* __restrict__ Wo, unsigned short* __restrict__ WoBf) {
    const int idx = blockIdx.x * 256 + threadIdx.x;
    if (idx < VOUT * HID) WoBf[idx] = f2bf(Wo[idx]);
}

// sequence [B, T, D] fp32 -> Xbf [T-1, B, D] bf16 (time-major for per-step contiguity)
__global__ void pack_x(const float* __restrict__ seq, unsigned short* __restrict__ Xbf) {
    const size_t idx = (size_t)blockIdx.x * 256 + threadIdx.x;
    if (idx >= (size_t)T_STEPS * BATCH * DIM) return;
    const int k = (int)(idx & (DIM - 1));
    const int b = (int)((idx >> 8) & (BATCH - 1));
    const int t = (int)(idx >> 15);
    Xbf[idx] = f2bf(seq[((size_t)b * T_SEQ + t) * DIM + k]);
}

__global__ void init_state(unsigned short* __restrict__ Hb, float* __restrict__ cbuf) {
    const int idx = blockIdx.x * 256 + threadIdx.x;
    if (idx < BATCH * HID) { Hb[idx] = 0; cbuf[idx] = 0.f; }
}

// ---------------- recurrent step kernel: one launch per timestep ----------------
// grid 256 WGs x 512 threads (1 WG/CU). WG bx: s = batch half (64 rows),
// g7 = h-col group (8 h-cols -> 32 gate cols). K = 1280 fused [x_t | h_{t-1}].
// 8 waves in 4x2 (rowgroups x colgroups), one 16x16x32 MFMA chain each.
// Epilogue: gates -> LDS -> fused cell update, write h_{t} bf16 to slot t+1.
__global__ __launch_bounds__(512, 2) void lstm_step(
    const unsigned short* __restrict__ Xbf,
    unsigned short* __restrict__ Hb,
    const unsigned short* __restrict__ Wp,
    const float* __restrict__ bc,
    float* __restrict__ cbuf,
    int t)
{
    const int bx = blockIdx.x;
    const int s  = bx & 1;
    const int g7 = bx >> 1;          // 0..127
    const int tid = threadIdx.x;
    const int w  = tid >> 6;         // wave 0..7
    const int l  = tid & 63;
    const int lr = l & 15;
    const int lq = l >> 4;
    const int rw = w >> 1;           // row group 0..3
    const int cw = w & 1;            // col group 0..1

    const int arow = s * 64 + rw * 16 + lr;   // batch row

    // A fragments: lane reads A[row][k0 + lq*8 .. +8] (16 B), k-contiguous layouts
    const unsigned short* ax = Xbf + ((size_t)t * BATCH + arow) * DIM + lq * 8;
    const unsigned short* ah = Hb + (size_t)t * BATCH * HID + (size_t)arow * HID + lq * 8;
    // B fragments: Wp[col][k], col = cw*16 + lr within this WG's 32 cols
    const unsigned short* bw = Wp + ((size_t)g7 * 32 + cw * 16 + lr) * KTOT + lq * 8;

    floatx4 acc = {0.f, 0.f, 0.f, 0.f};

    #pragma unroll
    for (int kk = 0; kk < 8; ++kk) {          // x part, k = 0..255
        short8 a = *(const short8*)(ax + kk * 32);
        short8 b = *(const short8*)(bw + kk * 32);
        acc = __builtin_amdgcn_mfma_f32_16x16x32_bf16(a, b, acc, 0, 0, 0);
    }
    #pragma unroll 8
    for (int kk = 0; kk < 32; ++kk) {         // h part, k = 256..1279
        short8 a = *(const short8*)(ah + kk * 32);
        short8 b = *(const short8*)(bw + 256 + kk * 32);
        acc = __builtin_amdgcn_mfma_f32_16x16x32_bf16(a, b, acc, 0, 0, 0);
    }

    // stage gates to LDS (C/D layout: col = lane&15, row = (lane>>4)*4 + reg)
    __shared__ float gl[64][33];
    #pragma unroll
    for (int r = 0; r < 4; ++r)
        gl[rw * 16 + lq * 4 + r][cw * 16 + lr] = acc[r];
    __syncthreads();

    // fused cell update: 512 threads = 64 rows x 8 h-cols
    const int r  = tid >> 3;
    const int jj = tid & 7;
    const float gi = gl[r][0  + jj] + bc[g7 * 32 + 0  + jj];
    const float gf = gl[r][8  + jj] + bc[g7 * 32 + 8  + jj];
    const float gg = gl[r][16 + jj] + bc[g7 * 32 + 16 + jj];
    const float go = gl[r][24 + jj] + bc[g7 * 32 + 24 + jj];
    const float iv = sigm(gi);
    const float fv = sigm(gf);
    const float gv = tanhf(gg);
    const float ov = sigm(go);
    const int b = s * 64 + r;
    const int j = g7 * 8 + jj;
    const size_t cidx = (size_t)b * HID + j;
    const float cn = fv * cbuf[cidx] + iv * gv;
    cbuf[cidx] = cn;
    Hb[(size_t)(t + 1) * BATCH * HID + cidx] = f2bf(ov * tanhf(cn));
}

// ---------------- deferred head: logits + log-softmax over all timesteps ----------------
// grid (8, 1023): WG = 16 batch rows x 128 logit cols for one t. 4 waves x 2 col-tiles.
__global__ __launch_bounds__(256, 2) void head_ls(
    const unsigned short* __restrict__ Hb,
    const unsigned short* __restrict__ Wo,
    const float* __restrict__ bo,
    float* __restrict__ out)
{
    const int bg = blockIdx.x;    // 0..7
    const int t  = blockIdx.y;    // 0..1022
    const int tid = threadIdx.x;
    const int w  = tid >> 6;
    const int l  = tid & 63;
    const int lr = l & 15;
    const int lq = l >> 4;
    const int b0 = bg * 16;

    const unsigned short* ap  = Hb + (size_t)(t + 1) * BATCH * HID + (size_t)(b0 + lr) * HID + lq * 8;
    const unsigned short* bp0 = Wo + (size_t)(w * 32 + lr) * HID + lq * 8;
    const unsigned short* bp1 = Wo + (size_t)(w * 32 + 16 + lr) * HID + lq * 8;

    floatx4 a0 = {0.f, 0.f, 0.f, 0.f}, a1 = {0.f, 0.f, 0.f, 0.f};
    #pragma unroll 8
    for (int kk = 0; kk < 32; ++kk) {
        short8 a  = *(const short8*)(ap + kk * 32);
        short8 b0v = *(const short8*)(bp0 + kk * 32);
        short8 b1v = *(const short8*)(bp1 + kk * 32);
        a0 = __builtin_amdgcn_mfma_f32_16x16x32_bf16(a, b0v, a0, 0, 0, 0);
        a1 = __builtin_amdgcn_mfma_f32_16x16x32_bf16(a, b1v, a1, 0, 0, 0);
    }

    __shared__ float lg[16][132];
    #pragma unroll
    for (int r = 0; r < 4; ++r) {
        lg[lq * 4 + r][w * 32 + lr]      = a0[r] + bo[w * 32 + lr];
        lg[lq * 4 + r][w * 32 + 16 + lr] = a1[r] + bo[w * 32 + 16 + lr];
    }
    __syncthreads();

    // log-softmax per row: 16 threads/row, 8 cols each
    const int row = tid >> 4;
    const int c   = tid & 15;
    float vals[8];
    float m = -1e30f;
    #pragma unroll
    for (int jv = 0; jv < 8; ++jv) { vals[jv] = lg[row][c + jv * 16]; m = fmaxf(m, vals[jv]); }
    #pragma unroll
    for (int d = 8; d >= 1; d >>= 1) m = fmaxf(m, __shfl_xor(m, d, 16));
    float ssum = 0.f;
    #pragma unroll
    for (int jv = 0; jv < 8; ++jv) ssum += __expf(vals[jv] - m);
    #pragma unroll
    for (int d = 8; d >= 1; d >>= 1) ssum += __shfl_xor(ssum, d, 16);
    const float lse = m + __logf(ssum);

    float* op = out + ((size_t)(b0 + row) * T_STEPS + t) * VOUT;
    #pragma unroll
    for (int jv = 0; jv < 8; ++jv) op[c + jv * 16] = vals[jv] - lse;
}

// ---------------- launcher ----------------
extern "C" void kernel_launch(void* const* d_in, const int* in_sizes, int n_in,
                              void* d_out, int out_size, void* d_ws, size_t ws_size,
                              hipStream_t stream) {
    const float* seq  = (const float*)d_in[0];
    const float* Wih  = (const float*)d_in[1];
    const float* Whh  = (const float*)d_in[2];
    const float* bih  = (const float*)d_in[3];
    const float* bhh  = (const float*)d_in[4];
    const float* Wout = (const float*)d_in[5];
    const float* bout = (const float*)d_in[6];
    float* out = (float*)d_out;

    // workspace carve (all 16B-aligned sizes); total ~347 MB
    char* p = (char*)d_ws;
    unsigned short* Wp   = (unsigned short*)p; p += (size_t)128 * 32 * KTOT * 2;       // 10.5 MB
    unsigned short* WoBf = (unsigned short*)p; p += (size_t)VOUT * HID * 2;            // 256 KB
    float*          bc   = (float*)p;          p += (size_t)4096 * 4;                  // 16 KB
    unsigned short* Xbf  = (unsigned short*)p; p += (size_t)T_STEPS * BATCH * DIM * 2; // 67 MB
    unsigned short* Hb   = (unsigned short*)p; p += (size_t)(T_STEPS + 1) * BATCH * HID * 2; // 268 MB
    float*          cbuf = (float*)p;          p += (size_t)BATCH * HID * 4;           // 512 KB

    pack_w    <<<20480, 256, 0, stream>>>(Wih, Whh, Wp);
    pack_bias <<<16,    256, 0, stream>>>(bih, bhh, bc);
    pack_wout <<<512,   256, 0, stream>>>(Wout, WoBf);
    pack_x    <<<130944,256, 0, stream>>>(seq, Xbf);
    init_state<<<512,   256, 0, stream>>>(Hb, cbuf);

    for (int t = 0; t < T_STEPS; ++t)
        lstm_step<<<256, 512, 0, stream>>>(Xbf, Hb, Wp, bc, cbuf, t);

    head_ls<<<dim3(8, T_STEPS), 256, 0, stream>>>(Hb, WoBf, bout, out);
}